// Round 3
// baseline (6858.163 us; speedup 1.0000x reference)
//
#include <hip/hip_runtime.h>

// Problem constants
#define Bb 128
#define Tt 512
#define Dd 1024
#define Hh 1024
#define KC 2048   // D + H (old fallback path)
#define NG 4096   // 4*H, gate-interleaved: n = 4*j + g
#define BH (Bb * Hh)

typedef __attribute__((ext_vector_type(4))) float f32x4;
typedef __attribute__((ext_vector_type(8))) short s16x8;

__device__ inline unsigned short f2bf(float f) {
  union { float f; unsigned int u; } x;
  x.f = f;
  unsigned int r = x.u + 0x7fffu + ((x.u >> 16) & 1u);  // RNE
  return (unsigned short)(r >> 16);
}
__device__ inline float bf2f(unsigned short u) {
  union { unsigned int u; float f; } x;
  x.u = ((unsigned int)u) << 16;
  return x.f;
}
__device__ inline float sigm(float x) {
  return __builtin_amdgcn_rcpf(1.f + __expf(-x));
}
__device__ inline float tanh_fast(float x) {
  return 2.f * __builtin_amdgcn_rcpf(1.f + __expf(-2.f * x)) - 1.f;
}
// async 16B global -> LDS (wave-uniform LDS base + lane*16 HW scatter; global
// source address is per-lane)
__device__ __forceinline__ void gl_lds16(void* lds, const void* g) {
  __builtin_amdgcn_global_load_lds(
      (const __attribute__((address_space(1))) unsigned int*)g,
      (__attribute__((address_space(3))) unsigned int*)lds, 16, 0, 0);
}

// ============================== NEW PATH =====================================

// Build gate-interleaved bf16 W_ih / W_hh, reordered bias, zero h-carrier and
// the group barrier counters.
__global__ void prep_new(const float* __restrict__ Wih,
                         const float* __restrict__ Whh,
                         const float* __restrict__ bias,
                         unsigned short* __restrict__ Wihr,
                         unsigned short* __restrict__ Whhr,
                         float* __restrict__ br,
                         unsigned short* __restrict__ hbf0,
                         unsigned int* __restrict__ cnt) {
  long tid0 = (long)blockIdx.x * blockDim.x + threadIdx.x;
  long stride = (long)gridDim.x * blockDim.x;
  const long wtot = (long)NG * 1024;
  for (long i = tid0; i < wtot; i += stride) {
    int n = (int)(i >> 10), k = (int)(i & 1023);
    int j = n >> 2, g = n & 3;
    Wihr[i] = f2bf(Wih[(size_t)(g * Hh + j) * Dd + k]);
    Whhr[i] = f2bf(Whh[(size_t)(g * Hh + j) * Hh + k]);
  }
  for (long i = tid0; i < NG; i += stride) {
    int j = (int)i >> 2, g = (int)i & 3;
    br[i] = bias[g * Hh + j];
  }
  for (long i = tid0; i < (long)Bb * Hh; i += stride) hbf0[i] = 0;
  for (long i = tid0; i < 256; i += stride) cnt[i] = 0u;
}

// xp[t*B + b][n] = (X @ Wihr^T), bf16 out. (Unchanged from round 2 — verified.)
__global__ __launch_bounds__(256)
void xproj_gemm(const float* __restrict__ X,
                const unsigned short* __restrict__ Wr,
                unsigned short* __restrict__ xp) {
  __shared__ unsigned short As[128 * 64];
  __shared__ unsigned short Bs[128 * 64];
  const int tid = threadIdx.x;
  const int lane = tid & 63, wave = tid >> 6;
  const int wr = wave >> 1, wc = wave & 1;

  int bid = blockIdx.x;
  int id2 = (bid & 7) * (16384 / 8) + (bid >> 3);
  const int m0 = (id2 >> 5) * 128;
  const int n0 = (id2 & 31) * 128;

  f32x4 acc[4][4];
#pragma unroll
  for (int m = 0; m < 4; m++)
#pragma unroll
    for (int n = 0; n < 4; n++) acc[m][n] = (f32x4){0.f, 0.f, 0.f, 0.f};

  const int arow = tid >> 1, ahalf = tid & 1;
  const float* abase = X + (size_t)(m0 + arow) * 1024 + ahalf * 32;

  for (int kc = 0; kc < 1024; kc += 64) {
#pragma unroll
    for (int r = 0; r < 4; r++) {
      int ch = wave * 4 + r;
      int row = ch * 8 + (lane >> 3);
      int slot = (lane & 7) ^ (row & 7);
      gl_lds16((char*)Bs + ch * 1024,
               Wr + (size_t)(n0 + row) * 1024 + kc + slot * 8);
    }
    float4 av[8];
    const float4* asrc = (const float4*)(abase + kc);
#pragma unroll
    for (int i = 0; i < 8; i++) av[i] = asrc[i];
    unsigned short ab[32];
#pragma unroll
    for (int i = 0; i < 8; i++) {
      ab[i * 4 + 0] = f2bf(av[i].x);
      ab[i * 4 + 1] = f2bf(av[i].y);
      ab[i * 4 + 2] = f2bf(av[i].z);
      ab[i * 4 + 3] = f2bf(av[i].w);
    }
#pragma unroll
    for (int i = 0; i < 4; i++) {
      int slot = (ahalf * 4 + i) ^ (arow & 7);
      *(uint4*)((char*)As + arow * 128 + slot * 16) = *(const uint4*)&ab[i * 8];
    }
    __syncthreads();
#pragma unroll
    for (int ks = 0; ks < 2; ks++) {
      s16x8 af[4], bfr[4];
#pragma unroll
      for (int m = 0; m < 4; m++) {
        int row = wr * 64 + m * 16 + (lane & 15);
        int slot = (ks * 4 + (lane >> 4)) ^ (row & 7);
        af[m] = *(const s16x8*)((const char*)As + row * 128 + slot * 16);
      }
#pragma unroll
      for (int n = 0; n < 4; n++) {
        int row = wc * 64 + n * 16 + (lane & 15);
        int slot = (ks * 4 + (lane >> 4)) ^ (row & 7);
        bfr[n] = *(const s16x8*)((const char*)Bs + row * 128 + slot * 16);
      }
#pragma unroll
      for (int m = 0; m < 4; m++)
#pragma unroll
        for (int n = 0; n < 4; n++)
          acc[m][n] = __builtin_amdgcn_mfma_f32_16x16x32_bf16(af[m], bfr[n],
                                                              acc[m][n], 0, 0, 0);
    }
    __syncthreads();
  }

#pragma unroll
  for (int m = 0; m < 4; m++) {
#pragma unroll
    for (int r = 0; r < 4; r++) {
      int gm = m0 + wr * 64 + m * 16 + ((lane >> 4) << 2) + r;
      int t = gm & (Tt - 1), b = gm >> 9;
      unsigned short* dst =
          xp + ((size_t)t * Bb + b) * NG + n0 + wc * 64 + (lane & 15);
#pragma unroll
      for (int n = 0; n < 4; n++) dst[n * 16] = f2bf(acc[m][n][r]);
    }
  }
}

// Persistent LSTM recurrence: 256 WGs (1/CU), 512 threads (8 waves).
// 4 independent batch groups of 32 rows; each group = 64 WGs spin-syncing on
// its own device-scope counter. W_hh slice lives in registers (breg[32], 128
// VGPR/lane) for all 512 steps; h staged to LDS per step via global_load_lds;
// c lives in 1 register/thread.
__global__ __launch_bounds__(512, 2)
void lstm_persist(const unsigned short* __restrict__ Whhr,  // [4096][1024] bf16
                  const float* __restrict__ br,             // [4096] reordered
                  const unsigned short* __restrict__ xp,    // [T][128][4096] bf16
                  unsigned short* __restrict__ hb0,         // [128][1024] bf16
                  unsigned short* __restrict__ hb1,
                  float* __restrict__ out,                  // [T][128][1024] ++ dh ++ dc
                  unsigned int* __restrict__ cnt) {         // 4 counters, 256B apart
  __shared__ __align__(16) char AsB[65536];  // [32 rows][128 slots of 16B]
  __shared__ float Gs[32][64];

  const int tid = threadIdx.x;
  const int lane = tid & 63, wave = tid >> 6;  // 8 waves
  const int wr = wave >> 2, wc = wave & 3;     // 2 m-halves x 4 n-quarters
  const int g = blockIdx.x & 3;                // batch group
  const int m0 = g * 32;
  const int n0 = (blockIdx.x >> 2) * 64;       // 64 gate cols = 16 hidden units
  unsigned int* mycnt = cnt + g * 64;

  // ---- W_hh slice into registers: wave covers n-rows n0+wc*16 .. +15 ----
  s16x8 breg[32];
  {
    const unsigned short* bsrc =
        Whhr + (size_t)(n0 + wc * 16 + (lane & 15)) * 1024 + ((lane >> 4) << 3);
#pragma unroll
    for (int ks = 0; ks < 32; ks++)
      breg[ks] = *(const s16x8*)(bsrc + ks * 32);
  }

  // pointwise mapping: thread -> (batch row, hidden unit)
  const int prow = tid >> 4;   // 0..31
  const int pjc = tid & 15;    // 0..15
  const int jg = (n0 >> 2) + pjc;
  const float4 bv = *(const float4*)(br + n0 + 4 * pjc);
  float creg = 0.f;

  const int arow = wr * 16 + (lane & 15);
  const int arow7 = arow & 7;
  const int klane = lane >> 4;

  for (int t = 0; t < Tt; t++) {
    const unsigned short* hin = (t & 1) ? hb1 : hb0;
    unsigned short* hnx = (t & 1) ? hb0 : hb1;

    // xp prefetch (4 bf16 per thread), flies under A staging + MFMA
    uint2 xv = *(const uint2*)(xp + (size_t)t * (Bb * NG) +
                               (size_t)(m0 + prow) * NG + n0 + 4 * pjc);

    // stage A = h[32][1024] bf16, XOR-swizzled, two K-halves of 512
#pragma unroll
    for (int h = 0; h < 2; h++)
#pragma unroll
      for (int i = 0; i < 4; i++) {
        int r = wave * 4 + i;
        gl_lds16(AsB + r * 2048 + h * 1024,
                 hin + (size_t)(m0 + r) * 1024 +
                     (((h * 64 + lane) ^ (r & 7)) << 3));
      }

    f32x4 acc = {0.f, 0.f, 0.f, 0.f};

    // wait half0 only (4 gl_lds16/wave remain in flight + counted slack)
    asm volatile("s_waitcnt vmcnt(4)" ::: "memory");
    __builtin_amdgcn_sched_barrier(0);
    __builtin_amdgcn_s_barrier();
#pragma unroll
    for (int ks = 0; ks < 16; ks++) {
      s16x8 af = *(const s16x8*)(AsB + arow * 2048 +
                                 (((ks * 4 + klane) ^ arow7) << 4));
      acc = __builtin_amdgcn_mfma_f32_16x16x32_bf16(af, breg[ks], acc, 0, 0, 0);
    }
    asm volatile("s_waitcnt vmcnt(0)" ::: "memory");
    __builtin_amdgcn_sched_barrier(0);
    __builtin_amdgcn_s_barrier();
#pragma unroll
    for (int ks = 16; ks < 32; ks++) {
      s16x8 af = *(const s16x8*)(AsB + arow * 2048 +
                                 (((ks * 4 + klane) ^ arow7) << 4));
      acc = __builtin_amdgcn_mfma_f32_16x16x32_bf16(af, breg[ks], acc, 0, 0, 0);
    }

    // acc -> Gs (C/D layout: col=lane&15, row=(lane>>4)*4+reg)
    {
      int colg = wc * 16 + (lane & 15);
      int rb = wr * 16 + ((lane >> 4) << 2);
#pragma unroll
      for (int r = 0; r < 4; r++) Gs[rb + r][colg] = acc[r];
    }
    __syncthreads();

    // pointwise LSTM (c in register)
    {
      float4 gv = *(const float4*)&Gs[prow][4 * pjc];
      float iv = gv.x + bf2f((unsigned short)(xv.x & 0xffffu)) + bv.x;
      float fv = gv.y + bf2f((unsigned short)(xv.x >> 16)) + bv.y;
      float gg = gv.z + bf2f((unsigned short)(xv.y & 0xffffu)) + bv.z;
      float ov = gv.w + bf2f((unsigned short)(xv.y >> 16)) + bv.w;
      float ig = sigm(iv), fg = sigm(fv), og = sigm(ov);
      float gt = tanh_fast(gg);
      creg = fg * creg + ig * gt;
      float hn = og * tanh_fast(creg);
      size_t oi = (size_t)(m0 + prow) * Hh + jg;
      out[(size_t)t * BH + oi] = hn;
      hnx[oi] = f2bf(hn);
      if (t == Tt - 1) {
        float* dh = out + (size_t)Tt * BH;
        dh[oi] = hn;        // h_last
        dh[BH + oi] = creg; // c_last
      }
    }
    __syncthreads();  // drains stores (vmcnt 0) per wave before release

    if (t < Tt - 1) {
      if (tid == 0) {
        __hip_atomic_fetch_add(mycnt, 1u, __ATOMIC_RELEASE,
                               __HIP_MEMORY_SCOPE_AGENT);
        unsigned int target = 64u * (unsigned int)(t + 1);
        while (__hip_atomic_load(mycnt, __ATOMIC_RELAXED,
                                 __HIP_MEMORY_SCOPE_AGENT) < target)
          __builtin_amdgcn_s_sleep(1);
        (void)__hip_atomic_load(mycnt, __ATOMIC_ACQUIRE,
                                __HIP_MEMORY_SCOPE_AGENT);
      }
      __syncthreads();
    }
  }
}

// ====================== OLD PATH (fallback, ws-limited) ======================

__global__ void prep_kernel(const float* __restrict__ Wih,
                            const float* __restrict__ Whh,
                            const float* __restrict__ bias,
                            unsigned short* __restrict__ Wr,
                            float* __restrict__ br,
                            float* __restrict__ c) {
  long tid0 = (long)blockIdx.x * blockDim.x + threadIdx.x;
  long stride = (long)gridDim.x * blockDim.x;
  const long total = (long)NG * KC;
  for (long idx = tid0; idx < total; idx += stride) {
    int n = (int)(idx >> 11);
    int k = (int)(idx & (KC - 1));
    int j = n >> 2, g = n & 3;
    float v;
    if (k < Dd) v = Wih[(size_t)(g * Hh + j) * Dd + k];
    else        v = Whh[(size_t)(g * Hh + j) * Hh + (k - Dd)];
    Wr[idx] = f2bf(v);
  }
  for (long idx = tid0; idx < NG; idx += stride) {
    int j = (int)idx >> 2, g = (int)idx & 3;
    br[idx] = bias[g * Hh + j];
  }
  for (long idx = tid0; idx < (long)Bb * Hh; idx += stride)
    c[idx] = 0.f;
}

__global__ __launch_bounds__(256)
void lstm_step(const float* __restrict__ xt,
               const float* __restrict__ hprev,
               const unsigned short* __restrict__ Wr,
               const float* __restrict__ br,
               float* __restrict__ c,
               float* __restrict__ hout) {
  __shared__ unsigned short As2[32][64 + 8];
  __shared__ unsigned short Bs2[64][64 + 8];
  __shared__ float Gs[32][64];

  const int tid = threadIdx.x;
  const int lane = tid & 63;
  const int wid = tid >> 6;
  const int wr = wid >> 1;
  const int wc = wid & 1;
  const int m0 = blockIdx.x * 32;
  const int n0 = blockIdx.y * 64;

  f32x4 acc0 = {0.f, 0.f, 0.f, 0.f};
  f32x4 acc1 = {0.f, 0.f, 0.f, 0.f};

  const int a_row = tid >> 3;
  const int a_k = (tid & 7) << 3;
  const int b_row = tid >> 2;
  const int b_k = (tid & 3) << 4;

  for (int kc = 0; kc < KC; kc += 64) {
    {
      int k = kc + a_k;
      float v[8];
      if (k < Dd) {
        const float4* s =
            (const float4*)(xt + (size_t)(m0 + a_row) * ((size_t)Tt * Dd) + k);
        float4 p0 = s[0], p1 = s[1];
        v[0] = p0.x; v[1] = p0.y; v[2] = p0.z; v[3] = p0.w;
        v[4] = p1.x; v[5] = p1.y; v[6] = p1.z; v[7] = p1.w;
      } else if (hprev) {
        const float4* s =
            (const float4*)(hprev + (size_t)(m0 + a_row) * Hh + (k - Dd));
        float4 p0 = s[0], p1 = s[1];
        v[0] = p0.x; v[1] = p0.y; v[2] = p0.z; v[3] = p0.w;
        v[4] = p1.x; v[5] = p1.y; v[6] = p1.z; v[7] = p1.w;
      } else {
#pragma unroll
        for (int e = 0; e < 8; e++) v[e] = 0.f;
      }
#pragma unroll
      for (int e = 0; e < 8; e++) As2[a_row][a_k + e] = f2bf(v[e]);
    }
    {
      const uint4* s = (const uint4*)(Wr + (size_t)(n0 + b_row) * KC + kc + b_k);
      uint4 p0 = s[0], p1 = s[1];
      *(uint4*)&Bs2[b_row][b_k] = p0;
      *(uint4*)&Bs2[b_row][b_k + 8] = p1;
    }
    __syncthreads();
#pragma unroll
    for (int ks = 0; ks < 64; ks += 32) {
      s16x8 af = *(const s16x8*)&As2[wr * 16 + (lane & 15)][ks + ((lane >> 4) << 3)];
      s16x8 bf0 = *(const s16x8*)&Bs2[wc * 32 + (lane & 15)][ks + ((lane >> 4) << 3)];
      s16x8 bf1 = *(const s16x8*)&Bs2[wc * 32 + 16 + (lane & 15)][ks + ((lane >> 4) << 3)];
      acc0 = __builtin_amdgcn_mfma_f32_16x16x32_bf16(af, bf0, acc0, 0, 0, 0);
      acc1 = __builtin_amdgcn_mfma_f32_16x16x32_bf16(af, bf1, acc1, 0, 0, 0);
    }
    __syncthreads();
  }

  {
    int colb = wc * 32 + (lane & 15);
    int rbase = wr * 16 + ((lane >> 4) << 2);
#pragma unroll
    for (int r = 0; r < 4; r++) Gs[rbase + r][colb] = acc0[r];
#pragma unroll
    for (int r = 0; r < 4; r++) Gs[rbase + r][colb + 16] = acc1[r];
  }
  __syncthreads();

  for (int e = tid; e < 512; e += 256) {
    int row = e >> 4;
    int jc = e & 15;
    int gi = jc << 2;
    float iv = Gs[row][gi + 0] + br[n0 + gi + 0];
    float fv = Gs[row][gi + 1] + br[n0 + gi + 1];
    float gv = Gs[row][gi + 2] + br[n0 + gi + 2];
    float ov = Gs[row][gi + 3] + br[n0 + gi + 3];
    int gb = m0 + row;
    int j = (n0 >> 2) + jc;
    float cv = c[(size_t)gb * Hh + j];
    float ig = 1.f / (1.f + __expf(-iv));
    float fg = 1.f / (1.f + __expf(-fv));
    float og = 1.f / (1.f + __expf(-ov));
    float gg = tanhf(gv);
    float cn = fg * cv + ig * gg;
    float hn = og * tanhf(cn);
    c[(size_t)gb * Hh + j] = cn;
    hout[(size_t)gb * Hh + j] = hn;
  }
}

__global__ void finalize_kernel(const float* __restrict__ hlast,
                                const float* __restrict__ c,
                                float* __restrict__ dh,
                                float* __restrict__ dc) {
  int i = blockIdx.x * 256 + threadIdx.x;
  if (i < Bb * Hh) {
    dh[i] = hlast[i];
    dc[i] = c[i];
  }
}

// ============================== LAUNCHER =====================================

extern "C" void kernel_launch(void* const* d_in, const int* in_sizes, int n_in,
                              void* d_out, int out_size, void* d_ws, size_t ws_size,
                              hipStream_t stream) {
  const float* x = (const float*)d_in[0];     // [B,T,D]
  const float* Wih = (const float*)d_in[1];   // [4H,D]
  const float* Whh = (const float*)d_in[2];   // [4H,H]
  const float* bias = (const float*)d_in[3];  // [4H]
  float* out = (float*)d_out;                 // [T,B,H] ++ [B,H] ++ [B,H]
  char* ws = (char*)d_ws;

  const size_t WHH_OFF = 0;
  const size_t WIH_OFF = 8ull << 20;
  const size_t BR_OFF = 16ull << 20;
  const size_t H0_OFF = 17ull << 20;
  const size_t H1_OFF = (17ull << 20) + (256ull << 10);
  const size_t CNT_OFF = (17ull << 20) + (512ull << 10);
  const size_t XP_OFF = 18ull << 20;
  const size_t NEED = XP_OFF + (size_t)Tt * Bb * NG * 2;  // ~530 MB

  if (ws_size >= NEED) {
    unsigned short* Whhr = (unsigned short*)(ws + WHH_OFF);
    unsigned short* Wihr = (unsigned short*)(ws + WIH_OFF);
    float* br = (float*)(ws + BR_OFF);
    unsigned short* hb0 = (unsigned short*)(ws + H0_OFF);
    unsigned short* hb1 = (unsigned short*)(ws + H1_OFF);
    unsigned int* cnt = (unsigned int*)(ws + CNT_OFF);
    unsigned short* xp = (unsigned short*)(ws + XP_OFF);

    prep_new<<<2048, 256, 0, stream>>>(Wih, Whh, bias, Wihr, Whhr, br, hb0, cnt);
    xproj_gemm<<<16384, 256, 0, stream>>>(x, Wihr, xp);
    lstm_persist<<<256, 512, 0, stream>>>(Whhr, br, xp, hb0, hb1, out, cnt);
  } else {
    // fallback: round-1 path (16.5 MB ws)
    unsigned short* Wr = (unsigned short*)ws;
    float* br = (float*)(ws + (size_t)NG * KC * 2);
    float* c = (float*)(ws + (size_t)NG * KC * 2 + (size_t)NG * 4);

    prep_kernel<<<1024, 256, 0, stream>>>(Wih, Whh, bias, Wr, br, c);
    dim3 grid(Bb / 32, NG / 64);
    for (int t = 0; t < Tt; t++) {
      const float* xt = x + (size_t)t * Dd;
      const float* hp = (t == 0) ? nullptr : out + (size_t)(t - 1) * Bb * Hh;
      lstm_step<<<grid, 256, 0, stream>>>(xt, hp, Wr, br, c,
                                          out + (size_t)t * Bb * Hh);
    }
    float* dh = out + (size_t)Tt * Bb * Hh;
    finalize_kernel<<<(Bb * Hh + 255) / 256, 256, 0, stream>>>(
        out + (size_t)(Tt - 1) * Bb * Hh, c, dh, dh + (size_t)Bb * Hh);
  }
}

// Round 4
// 3033.011 us; speedup vs baseline: 2.2612x; 2.2612x over previous
//
#include <hip/hip_runtime.h>

// Problem constants
#define Bb 128
#define Tt 512
#define Dd 1024
#define Hh 1024
#define KC 2048   // D + H (old fallback path)
#define NG 4096   // 4*H, gate-interleaved: n = 4*j + g
#define BH (Bb * Hh)

typedef __attribute__((ext_vector_type(4))) float f32x4;
typedef __attribute__((ext_vector_type(8))) short s16x8;

__device__ inline unsigned short f2bf(float f) {
  union { float f; unsigned int u; } x;
  x.f = f;
  unsigned int r = x.u + 0x7fffu + ((x.u >> 16) & 1u);  // RNE
  return (unsigned short)(r >> 16);
}
__device__ inline float bf2f(unsigned short u) {
  union { unsigned int u; float f; } x;
  x.u = ((unsigned int)u) << 16;
  return x.f;
}
__device__ inline float sigm(float x) {
  return __builtin_amdgcn_rcpf(1.f + __expf(-x));
}
__device__ inline float tanh_fast(float x) {
  return 2.f * __builtin_amdgcn_rcpf(1.f + __expf(-2.f * x)) - 1.f;
}
// async 16B global -> LDS (wave-uniform LDS base + lane*16 HW scatter; global
// source address is per-lane)
__device__ __forceinline__ void gl_lds16(void* lds, const void* g) {
  __builtin_amdgcn_global_load_lds(
      (const __attribute__((address_space(1))) unsigned int*)g,
      (__attribute__((address_space(3))) unsigned int*)lds, 16, 0, 0);
}

// ============================== NEW PATH =====================================

// Build gate-interleaved bf16 W_ih / W_hh, reordered bias, zero h-carrier and
// the claim/step counters.
__global__ void prep_new(const float* __restrict__ Wih,
                         const float* __restrict__ Whh,
                         const float* __restrict__ bias,
                         unsigned short* __restrict__ Wihr,
                         unsigned short* __restrict__ Whhr,
                         float* __restrict__ br,
                         unsigned short* __restrict__ hbf0,
                         unsigned int* __restrict__ cnt) {
  long tid0 = (long)blockIdx.x * blockDim.x + threadIdx.x;
  long stride = (long)gridDim.x * blockDim.x;
  const long wtot = (long)NG * 1024;
  for (long i = tid0; i < wtot; i += stride) {
    int n = (int)(i >> 10), k = (int)(i & 1023);
    int j = n >> 2, g = n & 3;
    Wihr[i] = f2bf(Wih[(size_t)(g * Hh + j) * Dd + k]);
    Whhr[i] = f2bf(Whh[(size_t)(g * Hh + j) * Hh + k]);
  }
  for (long i = tid0; i < NG; i += stride) {
    int j = (int)i >> 2, g = (int)i & 3;
    br[i] = bias[g * Hh + j];
  }
  for (long i = tid0; i < (long)Bb * Hh; i += stride) hbf0[i] = 0;
  for (long i = tid0; i < 2048; i += stride) cnt[i] = 0u;
}

// xp[t*B + b][n] = (X @ Wihr^T), bf16 out. (Verified in rounds 2-3.)
__global__ __launch_bounds__(256)
void xproj_gemm(const float* __restrict__ X,
                const unsigned short* __restrict__ Wr,
                unsigned short* __restrict__ xp) {
  __shared__ unsigned short As[128 * 64];
  __shared__ unsigned short Bs[128 * 64];
  const int tid = threadIdx.x;
  const int lane = tid & 63, wave = tid >> 6;
  const int wr = wave >> 1, wc = wave & 1;

  int bid = blockIdx.x;
  int id2 = (bid & 7) * (16384 / 8) + (bid >> 3);
  const int m0 = (id2 >> 5) * 128;
  const int n0 = (id2 & 31) * 128;

  f32x4 acc[4][4];
#pragma unroll
  for (int m = 0; m < 4; m++)
#pragma unroll
    for (int n = 0; n < 4; n++) acc[m][n] = (f32x4){0.f, 0.f, 0.f, 0.f};

  const int arow = tid >> 1, ahalf = tid & 1;
  const float* abase = X + (size_t)(m0 + arow) * 1024 + ahalf * 32;

  for (int kc = 0; kc < 1024; kc += 64) {
#pragma unroll
    for (int r = 0; r < 4; r++) {
      int ch = wave * 4 + r;
      int row = ch * 8 + (lane >> 3);
      int slot = (lane & 7) ^ (row & 7);
      gl_lds16((char*)Bs + ch * 1024,
               Wr + (size_t)(n0 + row) * 1024 + kc + slot * 8);
    }
    float4 av[8];
    const float4* asrc = (const float4*)(abase + kc);
#pragma unroll
    for (int i = 0; i < 8; i++) av[i] = asrc[i];
    unsigned short ab[32];
#pragma unroll
    for (int i = 0; i < 8; i++) {
      ab[i * 4 + 0] = f2bf(av[i].x);
      ab[i * 4 + 1] = f2bf(av[i].y);
      ab[i * 4 + 2] = f2bf(av[i].z);
      ab[i * 4 + 3] = f2bf(av[i].w);
    }
#pragma unroll
    for (int i = 0; i < 4; i++) {
      int slot = (ahalf * 4 + i) ^ (arow & 7);
      *(uint4*)((char*)As + arow * 128 + slot * 16) = *(const uint4*)&ab[i * 8];
    }
    __syncthreads();
#pragma unroll
    for (int ks = 0; ks < 2; ks++) {
      s16x8 af[4], bfr[4];
#pragma unroll
      for (int m = 0; m < 4; m++) {
        int row = wr * 64 + m * 16 + (lane & 15);
        int slot = (ks * 4 + (lane >> 4)) ^ (row & 7);
        af[m] = *(const s16x8*)((const char*)As + row * 128 + slot * 16);
      }
#pragma unroll
      for (int n = 0; n < 4; n++) {
        int row = wc * 64 + n * 16 + (lane & 15);
        int slot = (ks * 4 + (lane >> 4)) ^ (row & 7);
        bfr[n] = *(const s16x8*)((const char*)Bs + row * 128 + slot * 16);
      }
#pragma unroll
      for (int m = 0; m < 4; m++)
#pragma unroll
        for (int n = 0; n < 4; n++)
          acc[m][n] = __builtin_amdgcn_mfma_f32_16x16x32_bf16(af[m], bfr[n],
                                                              acc[m][n], 0, 0, 0);
    }
    __syncthreads();
  }

#pragma unroll
  for (int m = 0; m < 4; m++) {
#pragma unroll
    for (int r = 0; r < 4; r++) {
      int gm = m0 + wr * 64 + m * 16 + ((lane >> 4) << 2) + r;
      int t = gm & (Tt - 1), b = gm >> 9;
      unsigned short* dst =
          xp + ((size_t)t * Bb + b) * NG + n0 + wc * 64 + (lane & 15);
#pragma unroll
      for (int n = 0; n < 4; n++) dst[n * 16] = f2bf(acc[m][n][r]);
    }
  }
}

// Persistent LSTM recurrence, XCD-LOCAL groups:
// 256 WGs x 512 thr, LDS-forced 1 WG/CU => exactly 32 WGs per XCD.
// Group = XCD id (16 batch rows); each WG claims one 128-gate-col slice.
// h exchange stays in the XCD's coherent L2 (L1 is write-through); per-step
// sync = relaxed atomicAdd + relaxed spin + L1-only buffer_inv sc0. No
// compiler-generated acquire/release (no L2 flushes).
__global__ __launch_bounds__(512, 1)
void lstm_persist(const unsigned short* __restrict__ Whhr,  // [4096][1024] bf16
                  const float* __restrict__ br,             // [4096] reordered
                  const unsigned short* __restrict__ xp,    // [T][128][4096] bf16
                  unsigned short* __restrict__ hb0,         // [128][1024] bf16
                  unsigned short* __restrict__ hb1,
                  float* __restrict__ out,                  // [T][128][1024] ++ dh ++ dc
                  unsigned int* __restrict__ claim,         // 8 counters, 128B apart
                  unsigned int* __restrict__ scnt) {        // 8 counters, 128B apart
  __shared__ __align__(16) char AsB[16 * 2048];  // h tile [16 rows][128 slots x16B]
  __shared__ float Gs[16][132];                  // gate tile
  __shared__ char pad_[49152];                   // force 1 WG/CU (>80KB total)
  __shared__ unsigned int s_slot;

  const int tid = threadIdx.x;
  const int lane = tid & 63, wave = tid >> 6;  // 8 waves

  // ---- identify XCD, claim an n-slice ----
  int xcd;
  asm volatile("s_getreg_b32 %0, hwreg(HW_REG_XCC_ID)" : "=s"(xcd));
  xcd &= 7;
  if (tid == 0) {
    unsigned int s = __hip_atomic_fetch_add(claim + xcd * 32, 1u,
                                            __ATOMIC_RELAXED,
                                            __HIP_MEMORY_SCOPE_AGENT);
    s_slot = s;
  }
  __syncthreads();
  const unsigned int slotRaw = s_slot;
  const int slot = (int)(slotRaw & 31u);
  const int m0 = xcd * 16;          // batch rows of this group
  const int n0 = slot * 128;        // gate columns of this WG
  unsigned int* mycnt = scnt + xcd * 32;
  // keep pad_ alive (condition is physically impossible but not provable)
  if (slotRaw > 200u && tid == 0) out[0] = (float)pad_[0];

  // ---- W_hh slice into registers: wave covers gate rows n0+16*wave..+15 ----
  s16x8 breg[32];
  {
    const unsigned short* bsrc =
        Whhr + (size_t)(n0 + wave * 16 + (lane & 15)) * 1024 + ((lane >> 4) << 3);
#pragma unroll
    for (int ks = 0; ks < 32; ks++) breg[ks] = *(const s16x8*)(bsrc + ks * 32);
  }

  // pointwise mapping: thread -> (batch row, hidden unit)
  const int prow = tid >> 5;   // 0..15
  const int pjc = tid & 31;    // 0..31
  const int jg = (n0 >> 2) + pjc;
  const float4 bv = *(const float4*)(br + n0 + 4 * pjc);
  float creg = 0.f;

  const int arow = lane & 15;
  const int arow7 = arow & 7;
  const int klane = lane >> 4;

  for (int t = 0; t < Tt; t++) {
    const unsigned short* hin = (t & 1) ? hb1 : hb0;
    unsigned short* hnx = (t & 1) ? hb0 : hb1;

    // xp slice for this step (issued early; consumed in pointwise ~1us later)
    uint2 xv = *(const uint2*)(xp + ((size_t)t * Bb + (m0 + prow)) * NG +
                               n0 + 4 * pjc);

    // stage A = h[16][1024] bf16 into LDS, XOR-swizzled source, linear dest.
    // 32 chunks of 1KB (row-half); 4 per wave.
#pragma unroll
    for (int i = 0; i < 4; i++) {
      int ch = wave * 4 + i;
      int row = ch >> 1, half = ch & 1;
      gl_lds16(AsB + row * 2048 + half * 1024,
               hin + (size_t)(m0 + row) * 1024 +
                   (((half * 64 + lane) ^ (row & 7)) << 3));
    }

    asm volatile("s_waitcnt vmcnt(0)" ::: "memory");
    __builtin_amdgcn_sched_barrier(0);
    __builtin_amdgcn_s_barrier();
    __builtin_amdgcn_sched_barrier(0);

    // 32 MFMAs, two interleaved acc chains
    f32x4 acc_a = {0.f, 0.f, 0.f, 0.f};
    f32x4 acc_b = {0.f, 0.f, 0.f, 0.f};
#pragma unroll
    for (int ks = 0; ks < 32; ks += 2) {
      s16x8 af0 = *(const s16x8*)(AsB + arow * 2048 +
                                  (((ks * 4 + klane) ^ arow7) << 4));
      acc_a = __builtin_amdgcn_mfma_f32_16x16x32_bf16(af0, breg[ks], acc_a, 0, 0, 0);
      s16x8 af1 = *(const s16x8*)(AsB + arow * 2048 +
                                  ((((ks + 1) * 4 + klane) ^ arow7) << 4));
      acc_b = __builtin_amdgcn_mfma_f32_16x16x32_bf16(af1, breg[ks + 1], acc_b, 0, 0, 0);
    }
    f32x4 acc = acc_a + acc_b;

    // acc -> Gs (C/D layout: col=lane&15, row=(lane>>4)*4+reg)
    {
      int colg = wave * 16 + (lane & 15);
      int rb = (lane >> 4) << 2;
#pragma unroll
      for (int r = 0; r < 4; r++) Gs[rb + r][colg] = acc[r];
    }
    __syncthreads();

    // pointwise LSTM (c in register)
    {
      float4 gv = *(const float4*)&Gs[prow][4 * pjc];
      float iv = gv.x + bf2f((unsigned short)(xv.x & 0xffffu)) + bv.x;
      float fv = gv.y + bf2f((unsigned short)(xv.x >> 16)) + bv.y;
      float gg = gv.z + bf2f((unsigned short)(xv.y & 0xffffu)) + bv.z;
      float ov = gv.w + bf2f((unsigned short)(xv.y >> 16)) + bv.w;
      float ig = sigm(iv), fg = sigm(fv), og = sigm(ov);
      float gt = tanh_fast(gg);
      creg = fg * creg + ig * gt;
      float hn = og * tanh_fast(creg);
      size_t oi = (size_t)(m0 + prow) * Hh + jg;
      out[(size_t)t * BH + oi] = hn;
      hnx[oi] = f2bf(hn);
      if (t == Tt - 1) {
        float* dh = out + (size_t)Tt * BH;
        dh[oi] = hn;        // h_last
        dh[BH + oi] = creg; // c_last
      }
    }

    if (t < Tt - 1) {
      // all waves drain their stores (write-through L1 -> in L2), then arrive
      asm volatile("s_waitcnt vmcnt(0)" ::: "memory");
      __syncthreads();
      if (tid == 0) {
        __hip_atomic_fetch_add(mycnt, 1u, __ATOMIC_RELAXED,
                               __HIP_MEMORY_SCOPE_AGENT);
        unsigned int target = 32u * (unsigned int)(t + 1);
        while (__hip_atomic_load(mycnt, __ATOMIC_RELAXED,
                                 __HIP_MEMORY_SCOPE_AGENT) < target)
          __builtin_amdgcn_s_sleep(1);
        // L1-only invalidate so next h loads read fresh L2 data
        asm volatile("s_waitcnt vmcnt(0)\n\tbuffer_inv sc0" ::: "memory");
      }
      __syncthreads();
    }
  }
}

// ====================== OLD PATH (fallback, ws-limited) ======================

__global__ void prep_kernel(const float* __restrict__ Wih,
                            const float* __restrict__ Whh,
                            const float* __restrict__ bias,
                            unsigned short* __restrict__ Wr,
                            float* __restrict__ br,
                            float* __restrict__ c) {
  long tid0 = (long)blockIdx.x * blockDim.x + threadIdx.x;
  long stride = (long)gridDim.x * blockDim.x;
  const long total = (long)NG * KC;
  for (long idx = tid0; idx < total; idx += stride) {
    int n = (int)(idx >> 11);
    int k = (int)(idx & (KC - 1));
    int j = n >> 2, g = n & 3;
    float v;
    if (k < Dd) v = Wih[(size_t)(g * Hh + j) * Dd + k];
    else        v = Whh[(size_t)(g * Hh + j) * Hh + (k - Dd)];
    Wr[idx] = f2bf(v);
  }
  for (long idx = tid0; idx < NG; idx += stride) {
    int j = (int)idx >> 2, g = (int)idx & 3;
    br[idx] = bias[g * Hh + j];
  }
  for (long idx = tid0; idx < (long)Bb * Hh; idx += stride)
    c[idx] = 0.f;
}

__global__ __launch_bounds__(256)
void lstm_step(const float* __restrict__ xt,
               const float* __restrict__ hprev,
               const unsigned short* __restrict__ Wr,
               const float* __restrict__ br,
               float* __restrict__ c,
               float* __restrict__ hout) {
  __shared__ unsigned short As2[32][64 + 8];
  __shared__ unsigned short Bs2[64][64 + 8];
  __shared__ float Gs[32][64];

  const int tid = threadIdx.x;
  const int lane = tid & 63;
  const int wid = tid >> 6;
  const int wr = wid >> 1;
  const int wc = wid & 1;
  const int m0 = blockIdx.x * 32;
  const int n0 = blockIdx.y * 64;

  f32x4 acc0 = {0.f, 0.f, 0.f, 0.f};
  f32x4 acc1 = {0.f, 0.f, 0.f, 0.f};

  const int a_row = tid >> 3;
  const int a_k = (tid & 7) << 3;
  const int b_row = tid >> 2;
  const int b_k = (tid & 3) << 4;

  for (int kc = 0; kc < KC; kc += 64) {
    {
      int k = kc + a_k;
      float v[8];
      if (k < Dd) {
        const float4* s =
            (const float4*)(xt + (size_t)(m0 + a_row) * ((size_t)Tt * Dd) + k);
        float4 p0 = s[0], p1 = s[1];
        v[0] = p0.x; v[1] = p0.y; v[2] = p0.z; v[3] = p0.w;
        v[4] = p1.x; v[5] = p1.y; v[6] = p1.z; v[7] = p1.w;
      } else if (hprev) {
        const float4* s =
            (const float4*)(hprev + (size_t)(m0 + a_row) * Hh + (k - Dd));
        float4 p0 = s[0], p1 = s[1];
        v[0] = p0.x; v[1] = p0.y; v[2] = p0.z; v[3] = p0.w;
        v[4] = p1.x; v[5] = p1.y; v[6] = p1.z; v[7] = p1.w;
      } else {
#pragma unroll
        for (int e = 0; e < 8; e++) v[e] = 0.f;
      }
#pragma unroll
      for (int e = 0; e < 8; e++) As2[a_row][a_k + e] = f2bf(v[e]);
    }
    {
      const uint4* s = (const uint4*)(Wr + (size_t)(n0 + b_row) * KC + kc + b_k);
      uint4 p0 = s[0], p1 = s[1];
      *(uint4*)&Bs2[b_row][b_k] = p0;
      *(uint4*)&Bs2[b_row][b_k + 8] = p1;
    }
    __syncthreads();
#pragma unroll
    for (int ks = 0; ks < 64; ks += 32) {
      s16x8 af = *(const s16x8*)&As2[wr * 16 + (lane & 15)][ks + ((lane >> 4) << 3)];
      s16x8 bf0 = *(const s16x8*)&Bs2[wc * 32 + (lane & 15)][ks + ((lane >> 4) << 3)];
      s16x8 bf1 = *(const s16x8*)&Bs2[wc * 32 + 16 + (lane & 15)][ks + ((lane >> 4) << 3)];
      acc0 = __builtin_amdgcn_mfma_f32_16x16x32_bf16(af, bf0, acc0, 0, 0, 0);
      acc1 = __builtin_amdgcn_mfma_f32_16x16x32_bf16(af, bf1, acc1, 0, 0, 0);
    }
    __syncthreads();
  }

  {
    int colb = wc * 32 + (lane & 15);
    int rbase = wr * 16 + ((lane >> 4) << 2);
#pragma unroll
    for (int r = 0; r < 4; r++) Gs[rbase + r][colb] = acc0[r];
#pragma unroll
    for (int r = 0; r < 4; r++) Gs[rbase + r][colb + 16] = acc1[r];
  }
  __syncthreads();

  for (int e = tid; e < 512; e += 256) {
    int row = e >> 4;
    int jc = e & 15;
    int gi = jc << 2;
    float iv = Gs[row][gi + 0] + br[n0 + gi + 0];
    float fv = Gs[row][gi + 1] + br[n0 + gi + 1];
    float gv = Gs[row][gi + 2] + br[n0 + gi + 2];
    float ov = Gs[row][gi + 3] + br[n0 + gi + 3];
    int gb = m0 + row;
    int j = (n0 >> 2) + jc;
    float cv = c[(size_t)gb * Hh + j];
    float ig = 1.f / (1.f + __expf(-iv));
    float fg = 1.f / (1.f + __expf(-fv));
    float og = 1.f / (1.f + __expf(-ov));
    float gg = tanhf(gv);
    float cn = fg * cv + ig * gg;
    float hn = og * tanhf(cn);
    c[(size_t)gb * Hh + j] = cn;
    hout[(size_t)gb * Hh + j] = hn;
  }
}

__global__ void finalize_kernel(const float* __restrict__ hlast,
                                const float* __restrict__ c,
                                float* __restrict__ dh,
                                float* __restrict__ dc) {
  int i = blockIdx.x * 256 + threadIdx.x;
  if (i < Bb * Hh) {
    dh[i] = hlast[i];
    dc[i] = c[i];
  }
}

// ============================== LAUNCHER =====================================

extern "C" void kernel_launch(void* const* d_in, const int* in_sizes, int n_in,
                              void* d_out, int out_size, void* d_ws, size_t ws_size,
                              hipStream_t stream) {
  const float* x = (const float*)d_in[0];     // [B,T,D]
  const float* Wih = (const float*)d_in[1];   // [4H,D]
  const float* Whh = (const float*)d_in[2];   // [4H,H]
  const float* bias = (const float*)d_in[3];  // [4H]
  float* out = (float*)d_out;                 // [T,B,H] ++ [B,H] ++ [B,H]
  char* ws = (char*)d_ws;

  const size_t WHH_OFF = 0;
  const size_t WIH_OFF = 8ull << 20;
  const size_t BR_OFF = 16ull << 20;
  const size_t H0_OFF = 17ull << 20;
  const size_t H1_OFF = (17ull << 20) + (256ull << 10);
  const size_t CNT_OFF = (17ull << 20) + (512ull << 10);
  const size_t XP_OFF = 18ull << 20;
  const size_t NEED = XP_OFF + (size_t)Tt * Bb * NG * 2;  // ~530 MB

  if (ws_size >= NEED) {
    unsigned short* Whhr = (unsigned short*)(ws + WHH_OFF);
    unsigned short* Wihr = (unsigned short*)(ws + WIH_OFF);
    float* br = (float*)(ws + BR_OFF);
    unsigned short* hb0 = (unsigned short*)(ws + H0_OFF);
    unsigned short* hb1 = (unsigned short*)(ws + H1_OFF);
    unsigned int* cnt = (unsigned int*)(ws + CNT_OFF);   // 2048 uints zeroed
    unsigned short* xp = (unsigned short*)(ws + XP_OFF);

    prep_new<<<2048, 256, 0, stream>>>(Wih, Whh, bias, Wihr, Whhr, br, hb0, cnt);
    xproj_gemm<<<16384, 256, 0, stream>>>(x, Wihr, xp);
    lstm_persist<<<256, 512, 0, stream>>>(Whhr, br, xp, hb0, hb1, out,
                                          cnt, cnt + 1024);
  } else {
    // fallback: round-1 path (16.5 MB ws)
    unsigned short* Wr = (unsigned short*)ws;
    float* br = (float*)(ws + (size_t)NG * KC * 2);
    float* c = (float*)(ws + (size_t)NG * KC * 2 + (size_t)NG * 4);

    prep_kernel<<<1024, 256, 0, stream>>>(Wih, Whh, bias, Wr, br, c);
    dim3 grid(Bb / 32, NG / 64);
    for (int t = 0; t < Tt; t++) {
      const float* xt = x + (size_t)t * Dd;
      const float* hp = (t == 0) ? nullptr : out + (size_t)(t - 1) * Bb * Hh;
      lstm_step<<<grid, 256, 0, stream>>>(xt, hp, Wr, br, c,
                                          out + (size_t)t * Bb * Hh);
    }
    float* dh = out + (size_t)Tt * Bb * Hh;
    finalize_kernel<<<(Bb * Hh + 255) / 256, 256, 0, stream>>>(
        out + (size_t)(Tt - 1) * Bb * Hh, c, dh, dh + (size_t)Bb * Hh);
  }
}